// Round 1
// baseline (1707.660 us; speedup 1.0000x reference)
//
#include <hip/hip_runtime.h>
#include <hip/hip_bf16.h>

// MHA forward: B=4, S=2048, D_MODEL=1024, H=16, Dk=64, scale=1/8.
// Outputs (concat in d_out): out [4,2048,1024] fp32, attn [4,16,2048,2048] fp32.
// Workspace: qp(16MB) kp(16MB) vt(16MB) oh(16MB) bf16 = 64MB.

typedef __attribute__((ext_vector_type(8))) short bf16x8;
typedef __attribute__((ext_vector_type(4))) float f32x4;

#define MFMA16(a, b, c) __builtin_amdgcn_mfma_f32_16x16x32_bf16(a, b, c, 0, 0, 0)

__device__ __forceinline__ unsigned short f2bf(float f) {
    union { float f; unsigned u; } v; v.f = f;
    return (unsigned short)((v.u + 0x7fffu + ((v.u >> 16) & 1u)) >> 16);
}
__device__ __forceinline__ float bf2f(unsigned short u) {
    union { unsigned u; float f; } v; v.u = ((unsigned)u) << 16;
    return v.f;
}

// ---------------------------------------------------------------------------
// Projection GEMM: P = X[8192,1024] @ W^T[1024,1024] + bias, output bf16.
// z=0 -> qp [8192,1024], z=1 -> kp [8192,1024], z=2 -> vt [64bh][64d][2048s].
// 128x128 block tile, BK=32, 256 threads (4 waves, each 64x64).
// ---------------------------------------------------------------------------
__global__ __launch_bounds__(256) void proj_gemm(
    const float* __restrict__ q, const float* __restrict__ k, const float* __restrict__ v,
    const float* __restrict__ wq, const float* __restrict__ wk, const float* __restrict__ wv,
    const float* __restrict__ bq, const float* __restrict__ bk, const float* __restrict__ bv,
    unsigned short* __restrict__ qp, unsigned short* __restrict__ kp,
    unsigned short* __restrict__ vt)
{
    const int z = blockIdx.z;
    const float* X    = (z == 0) ? q  : (z == 1) ? k  : v;
    const float* W    = (z == 0) ? wq : (z == 1) ? wk : wv;
    const float* Bias = (z == 0) ? bq : (z == 1) ? bk : bv;

    const int m0 = blockIdx.x * 128;
    const int n0 = blockIdx.y * 128;
    const int tid  = threadIdx.x;
    const int wave = tid >> 6;
    const int lane = tid & 63;
    const int quad = lane >> 4, ln = lane & 15;
    const int wm = (wave & 1) * 64, wn = (wave >> 1) * 64;

    // stride 72 elems = 144B: 16B-aligned rows, bank offset 4/row (2-way = free)
    __shared__ unsigned short As[128][72];
    __shared__ unsigned short Bs[128][72];

    f32x4 acc[4][4];
#pragma unroll
    for (int i = 0; i < 4; ++i)
#pragma unroll
        for (int j = 0; j < 4; ++j) acc[i][j] = (f32x4){0.f, 0.f, 0.f, 0.f};

    for (int kb = 0; kb < 1024; kb += 32) {
        __syncthreads();
        // stage A: 128 rows x 32 fp32 -> bf16
#pragma unroll
        for (int i = 0; i < 4; ++i) {
            int idx = tid + i * 256;             // 0..1023
            int row = idx >> 3, kc = (idx & 7) * 4;
            float4 f = *(const float4*)&X[(size_t)(m0 + row) * 1024 + kb + kc];
            unsigned short* dst = &As[row][kc];
            dst[0] = f2bf(f.x); dst[1] = f2bf(f.y); dst[2] = f2bf(f.z); dst[3] = f2bf(f.w);
        }
        // stage B (W rows = output cols)
#pragma unroll
        for (int i = 0; i < 4; ++i) {
            int idx = tid + i * 256;
            int row = idx >> 3, kc = (idx & 7) * 4;
            float4 f = *(const float4*)&W[(size_t)(n0 + row) * 1024 + kb + kc];
            unsigned short* dst = &Bs[row][kc];
            dst[0] = f2bf(f.x); dst[1] = f2bf(f.y); dst[2] = f2bf(f.z); dst[3] = f2bf(f.w);
        }
        __syncthreads();

        bf16x8 af[4], bfr[4];
#pragma unroll
        for (int mt = 0; mt < 4; ++mt)
            af[mt] = *(const bf16x8*)&As[wm + mt * 16 + ln][quad * 8];
#pragma unroll
        for (int nt = 0; nt < 4; ++nt)
            bfr[nt] = *(const bf16x8*)&Bs[wn + nt * 16 + ln][quad * 8];
#pragma unroll
        for (int mt = 0; mt < 4; ++mt)
#pragma unroll
            for (int nt = 0; nt < 4; ++nt)
                acc[mt][nt] = MFMA16(af[mt], bfr[nt], acc[mt][nt]);
    }

    float bias[4];
#pragma unroll
    for (int nt = 0; nt < 4; ++nt) bias[nt] = Bias[n0 + wn + nt * 16 + ln];

    if (z < 2) {
        unsigned short* OutP = (z == 0) ? qp : kp;
#pragma unroll
        for (int mt = 0; mt < 4; ++mt)
#pragma unroll
            for (int nt = 0; nt < 4; ++nt) {
                int col  = n0 + wn + nt * 16 + ln;
                int rowb = m0 + wm + mt * 16 + quad * 4;
#pragma unroll
                for (int j = 0; j < 4; ++j)
                    OutP[(size_t)(rowb + j) * 1024 + col] = f2bf(acc[mt][nt][j] + bias[nt]);
            }
    } else {
        // V transposed: vt[((b*16+h)*64 + d)*2048 + s]; 4 consecutive s -> 8B store
#pragma unroll
        for (int mt = 0; mt < 4; ++mt)
#pragma unroll
            for (int nt = 0; nt < 4; ++nt) {
                int col  = n0 + wn + nt * 16 + ln;       // n = h*64+d
                int rowb = m0 + wm + mt * 16 + quad * 4; // i = b*2048+s
                int bb = rowb >> 11, s = rowb & 2047;
                int hh = col >> 6,  d = col & 63;
                ushort4 pk;
                pk.x = f2bf(acc[mt][nt][0] + bias[nt]);
                pk.y = f2bf(acc[mt][nt][1] + bias[nt]);
                pk.z = f2bf(acc[mt][nt][2] + bias[nt]);
                pk.w = f2bf(acc[mt][nt][3] + bias[nt]);
                *(ushort4*)&vt[((size_t)((bb * 16 + hh) * 64 + d)) * 2048 + s] = pk;
            }
    }
}

// ---------------------------------------------------------------------------
// Attention: per block = one (b,h) x 128 q-rows. 4 waves, each owns 32 rows
// end-to-end (no __syncthreads anywhere). Two passes over t:
//   pass 1: online row max/sum;  pass 2: final P -> attn global + PV accumulate.
// ---------------------------------------------------------------------------
__global__ __launch_bounds__(256, 2) void attn_kernel(
    const unsigned short* __restrict__ qp, const unsigned short* __restrict__ kp,
    const unsigned short* __restrict__ vt, unsigned short* __restrict__ oh,
    float* __restrict__ attn)
{
    const int qt = blockIdx.x;   // 0..15
    const int bh = blockIdx.y;   // 0..63
    const int b = bh >> 4, h = bh & 15;
    const int tid  = threadIdx.x;
    const int wave = tid >> 6;
    const int lane = tid & 63;
    const int quad = lane >> 4, ln = lane & 15;
    const int q0 = qt * 128;
    const int rowbase = q0 + wave * 32;

    // per-wave private 32-row stripes; stride 136 elems = 272B (16B-aligned)
    __shared__ unsigned short P[128][136];

    const size_t qk_base = (size_t)b * 2048 * 1024 + (size_t)h * 64;
    const size_t v_base  = (size_t)bh * 64 * 2048;

    // Q fragments, resident all kernel: [rowT 2][kstep 2]
    bf16x8 aq[2][2];
#pragma unroll
    for (int r = 0; r < 2; ++r)
#pragma unroll
        for (int ks = 0; ks < 2; ++ks)
            aq[r][ks] = *(const bf16x8*)
                &qp[qk_base + (size_t)(rowbase + r * 16 + ln) * 1024 + ks * 32 + quad * 8];

    float m_run[2][4], l_run[2][4];
#pragma unroll
    for (int r = 0; r < 2; ++r)
#pragma unroll
        for (int j = 0; j < 4; ++j) { m_run[r][j] = -1e30f; l_run[r][j] = 0.f; }

    // ---- pass 1: stats ----
    for (int t0 = 0; t0 < 2048; t0 += 128) {
        f32x4 s[2][8];
#pragma unroll
        for (int r = 0; r < 2; ++r)
#pragma unroll
            for (int c = 0; c < 8; ++c) s[r][c] = (f32x4){0.f, 0.f, 0.f, 0.f};
#pragma unroll
        for (int ks = 0; ks < 2; ++ks)
#pragma unroll
            for (int c = 0; c < 8; ++c) {
                bf16x8 bk = *(const bf16x8*)
                    &kp[qk_base + (size_t)(t0 + c * 16 + ln) * 1024 + ks * 32 + quad * 8];
                s[0][c] = MFMA16(aq[0][ks], bk, s[0][c]);
                s[1][c] = MFMA16(aq[1][ks], bk, s[1][c]);
            }
#pragma unroll
        for (int r = 0; r < 2; ++r)
#pragma unroll
            for (int j = 0; j < 4; ++j) {
                float mt = -1e30f;
#pragma unroll
                for (int c = 0; c < 8; ++c) mt = fmaxf(mt, s[r][c][j]);
                mt = fmaxf(mt, __shfl_xor(mt, 1));
                mt = fmaxf(mt, __shfl_xor(mt, 2));
                mt = fmaxf(mt, __shfl_xor(mt, 4));
                mt = fmaxf(mt, __shfl_xor(mt, 8));
                mt *= 0.125f;                       // scale the (positive-scale) max
                float mn = fmaxf(m_run[r][j], mt);
                float sum = 0.f;
#pragma unroll
                for (int c = 0; c < 8; ++c) sum += __expf(s[r][c][j] * 0.125f - mn);
                sum += __shfl_xor(sum, 1);
                sum += __shfl_xor(sum, 2);
                sum += __shfl_xor(sum, 4);
                sum += __shfl_xor(sum, 8);
                l_run[r][j] = l_run[r][j] * __expf(m_run[r][j] - mn) + sum;
                m_run[r][j] = mn;
            }
    }

    float inv_l[2][4];
#pragma unroll
    for (int r = 0; r < 2; ++r)
#pragma unroll
        for (int j = 0; j < 4; ++j) inv_l[r][j] = 1.f / l_run[r][j];

    f32x4 o[2][4];
#pragma unroll
    for (int r = 0; r < 2; ++r)
#pragma unroll
        for (int dt = 0; dt < 4; ++dt) o[r][dt] = (f32x4){0.f, 0.f, 0.f, 0.f};

    // ---- pass 2: P -> attn + PV ----
    for (int t0 = 0; t0 < 2048; t0 += 128) {
        f32x4 s[2][8];
#pragma unroll
        for (int r = 0; r < 2; ++r)
#pragma unroll
            for (int c = 0; c < 8; ++c) s[r][c] = (f32x4){0.f, 0.f, 0.f, 0.f};
#pragma unroll
        for (int ks = 0; ks < 2; ++ks)
#pragma unroll
            for (int c = 0; c < 8; ++c) {
                bf16x8 bk = *(const bf16x8*)
                    &kp[qk_base + (size_t)(t0 + c * 16 + ln) * 1024 + ks * 32 + quad * 8];
                s[0][c] = MFMA16(aq[0][ks], bk, s[0][c]);
                s[1][c] = MFMA16(aq[1][ks], bk, s[1][c]);
            }
        // final P values -> LDS (bf16), wave-private stripe
#pragma unroll
        for (int r = 0; r < 2; ++r)
#pragma unroll
            for (int c = 0; c < 8; ++c) {
                const int prow = wave * 32 + r * 16 + quad * 4;
                const int pcol = c * 16 + ln;
#pragma unroll
                for (int j = 0; j < 4; ++j) {
                    float p = __expf(s[r][c][j] * 0.125f - m_run[r][j]) * inv_l[r][j];
                    P[prow + j][pcol] = f2bf(p);
                }
            }
        // coalesced attn store from LDS (own 32 rows; lane -> 2 cols)
#pragma unroll
        for (int r = 0; r < 32; ++r) {
            const int row = wave * 32 + r;
            unsigned pk = *(const unsigned*)&P[row][lane * 2];
            float2 f2;
            f2.x = bf2f((unsigned short)(pk & 0xffffu));
            f2.y = bf2f((unsigned short)(pk >> 16));
            *(float2*)&attn[((size_t)(bh * 2048 + q0 + row)) * 2048 + t0 + lane * 2] = f2;
        }
        // PV: O += P[32 x 128] @ V[128 x 64]  (B-frags from pre-transposed vt)
#pragma unroll
        for (int kt = 0; kt < 4; ++kt) {
            bf16x8 ap0 = *(const bf16x8*)&P[wave * 32 + ln][kt * 32 + quad * 8];
            bf16x8 ap1 = *(const bf16x8*)&P[wave * 32 + 16 + ln][kt * 32 + quad * 8];
#pragma unroll
            for (int dt = 0; dt < 4; ++dt) {
                bf16x8 bv = *(const bf16x8*)
                    &vt[v_base + (size_t)(dt * 16 + ln) * 2048 + t0 + kt * 32 + quad * 8];
                o[0][dt] = MFMA16(ap0, bv, o[0][dt]);
                o[1][dt] = MFMA16(ap1, bv, o[1][dt]);
            }
        }
    }

    // epilogue: oh [B,S,1024] bf16 (heads re-interleaved)
#pragma unroll
    for (int r = 0; r < 2; ++r)
#pragma unroll
        for (int dt = 0; dt < 4; ++dt) {
            const int rowb = b * 2048 + rowbase + r * 16 + quad * 4;
            const int col  = h * 64 + dt * 16 + ln;
#pragma unroll
            for (int j = 0; j < 4; ++j)
                oh[(size_t)(rowb + j) * 1024 + col] = f2bf(o[r][dt][j]);
        }
}

// ---------------------------------------------------------------------------
// Output GEMM: out[8192,1024] fp32 = oh(bf16) @ wo^T + bo
// ---------------------------------------------------------------------------
__global__ __launch_bounds__(256) void out_gemm(
    const unsigned short* __restrict__ oh, const float* __restrict__ wo,
    const float* __restrict__ bo, float* __restrict__ out)
{
    const int m0 = blockIdx.x * 128;
    const int n0 = blockIdx.y * 128;
    const int tid  = threadIdx.x;
    const int wave = tid >> 6;
    const int lane = tid & 63;
    const int quad = lane >> 4, ln = lane & 15;
    const int wm = (wave & 1) * 64, wn = (wave >> 1) * 64;

    __shared__ unsigned short As[128][72];
    __shared__ unsigned short Bs[128][72];

    f32x4 acc[4][4];
#pragma unroll
    for (int i = 0; i < 4; ++i)
#pragma unroll
        for (int j = 0; j < 4; ++j) acc[i][j] = (f32x4){0.f, 0.f, 0.f, 0.f};

    for (int kb = 0; kb < 1024; kb += 32) {
        __syncthreads();
        // stage A (already bf16): 128x32 = 4096 bf16, 2 x uint4 per thread
#pragma unroll
        for (int i = 0; i < 2; ++i) {
            int idx = tid + i * 256;             // 0..511
            int row = idx >> 2, kc = (idx & 3) * 8;
            *(uint4*)&As[row][kc] = *(const uint4*)&oh[(size_t)(m0 + row) * 1024 + kb + kc];
        }
        // stage B from fp32 wo
#pragma unroll
        for (int i = 0; i < 4; ++i) {
            int idx = tid + i * 256;
            int row = idx >> 3, kc = (idx & 7) * 4;
            float4 f = *(const float4*)&wo[(size_t)(n0 + row) * 1024 + kb + kc];
            unsigned short* dst = &Bs[row][kc];
            dst[0] = f2bf(f.x); dst[1] = f2bf(f.y); dst[2] = f2bf(f.z); dst[3] = f2bf(f.w);
        }
        __syncthreads();

        bf16x8 af[4], bfr[4];
#pragma unroll
        for (int mt = 0; mt < 4; ++mt)
            af[mt] = *(const bf16x8*)&As[wm + mt * 16 + ln][quad * 8];
#pragma unroll
        for (int nt = 0; nt < 4; ++nt)
            bfr[nt] = *(const bf16x8*)&Bs[wn + nt * 16 + ln][quad * 8];
#pragma unroll
        for (int mt = 0; mt < 4; ++mt)
#pragma unroll
            for (int nt = 0; nt < 4; ++nt)
                acc[mt][nt] = MFMA16(af[mt], bfr[nt], acc[mt][nt]);
    }

    float bias[4];
#pragma unroll
    for (int nt = 0; nt < 4; ++nt) bias[nt] = bo[n0 + wn + nt * 16 + ln];

#pragma unroll
    for (int mt = 0; mt < 4; ++mt)
#pragma unroll
        for (int nt = 0; nt < 4; ++nt) {
            int col  = n0 + wn + nt * 16 + ln;
            int rowb = m0 + wm + mt * 16 + quad * 4;
#pragma unroll
            for (int j = 0; j < 4; ++j)
                out[(size_t)(rowb + j) * 1024 + col] = acc[mt][nt][j] + bias[nt];
        }
}

extern "C" void kernel_launch(void* const* d_in, const int* in_sizes, int n_in,
                              void* d_out, int out_size, void* d_ws, size_t ws_size,
                              hipStream_t stream) {
    const float* q  = (const float*)d_in[0];
    const float* k  = (const float*)d_in[1];
    const float* v  = (const float*)d_in[2];
    const float* wq = (const float*)d_in[3];
    const float* bq = (const float*)d_in[4];
    const float* wk = (const float*)d_in[5];
    const float* bk = (const float*)d_in[6];
    const float* wv = (const float*)d_in[7];
    const float* bv = (const float*)d_in[8];
    const float* wo = (const float*)d_in[9];
    const float* bo = (const float*)d_in[10];

    float* out  = (float*)d_out;
    float* attn = out + (size_t)8192 * 1024;   // outputs concatenated flat

    unsigned short* qp = (unsigned short*)d_ws;            // [8192,1024] bf16
    unsigned short* kp = qp + (size_t)8192 * 1024;         // [8192,1024] bf16
    unsigned short* vt = kp + (size_t)8192 * 1024;         // [64,64,2048] bf16
    unsigned short* oh = vt + (size_t)8192 * 1024;         // [8192,1024] bf16

    proj_gemm<<<dim3(64, 8, 3), 256, 0, stream>>>(q, k, v, wq, wk, wv, bq, bk, bv, qp, kp, vt);
    attn_kernel<<<dim3(16, 64), 256, 0, stream>>>(qp, kp, vt, oh, attn);
    out_gemm<<<dim3(64, 8), 256, 0, stream>>>(oh, wo, bo, out);
}